// Round 1
// baseline (535.777 us; speedup 1.0000x reference)
//
#include <hip/hip_runtime.h>
#include <math.h>

#define N_DET 1344
#define NW 21   // N_DET / 64 == 21 exactly

// ---------------- device helpers ----------------

// cr = e0*r1 - e1*r0 with coord0=qx, coord1=qy (matches reference component order)
__device__ __forceinline__ bool pt_in_quad4(const float* qx, const float* qy,
                                            float px, float py) {
    bool allp = true, alln = true;
#pragma unroll
    for (int k = 0; k < 4; k++) {
        int k1 = (k + 1) & 3;
        float ex = qx[k1] - qx[k], ey = qy[k1] - qy[k];
        float rx = px - qx[k],     ry = py - qy[k];
        float cr = ex * ry - ey * rx;
        allp = allp && (cr >= 0.f);
        alln = alln && (cr <= 0.f);
    }
    return allp || alln;
}

__device__ float quad_inter_area(const float* Ax, const float* Ay,
                                 const float* Bx, const float* By) {
    float px[24], py[24];
    unsigned vmask = 0;
    int n = 0;
#pragma unroll
    for (int k = 0; k < 4; k++) {         // A corners, valid if inside B
        px[k] = Ax[k]; py[k] = Ay[k];
        if (pt_in_quad4(Bx, By, Ax[k], Ay[k])) { vmask |= 1u << k; n++; }
    }
#pragma unroll
    for (int k = 0; k < 4; k++) {         // B corners, valid if inside A
        px[4 + k] = Bx[k]; py[4 + k] = By[k];
        if (pt_in_quad4(Ax, Ay, Bx[k], By[k])) { vmask |= 1u << (4 + k); n++; }
    }
#pragma unroll
    for (int k = 0; k < 4; k++) {
        int k1 = (k + 1) & 3;
        float rax = Ax[k1] - Ax[k], ray = Ay[k1] - Ay[k];
#pragma unroll
        for (int l = 0; l < 4; l++) {
            int l1 = (l + 1) & 3;
            float rbx = Bx[l1] - Bx[l], rby = By[l1] - By[l];
            float qpx = Bx[l] - Ax[k],  qpy = By[l] - Ay[k];
            float den = rax * rby - ray * rbx;
            float ad  = fabsf(den);
            float dsafe = (ad < 1e-9f) ? 1e-9f : den;
            float t = (qpx * rby - qpy * rbx) / dsafe;
            float u = (qpx * ray - qpy * rax) / dsafe;
            bool ok = (ad > 1e-9f) && t >= 0.f && t <= 1.f && u >= 0.f && u <= 1.f;
            int id = 8 + k * 4 + l;
            px[id] = Ax[k] + t * rax;
            py[id] = Ay[k] + t * ray;
            if (ok) { vmask |= 1u << id; n++; }
        }
    }
    float cx = 0.f, cy = 0.f;
#pragma unroll
    for (int m = 0; m < 24; m++)
        if ((vmask >> m) & 1u) { cx += px[m]; cy += py[m]; }
    int mx = (n < 1) ? 1 : n;
    cx = cx / (float)mx;
    cy = cy / (float)mx;
    float ang[24];
#pragma unroll
    for (int m = 0; m < 24; m++) {
        px[m] -= cx; py[m] -= cy;
        ang[m] = ((vmask >> m) & 1u) ? atan2f(py[m], px[m]) : 1e9f;
    }
    // stable insertion sort (ascending angle) — matches stable jnp.argsort
    int ord[24];
#pragma unroll
    for (int m = 0; m < 24; m++) ord[m] = m;
    for (int m = 1; m < 24; m++) {
        int o = ord[m];
        float av = ang[o];
        int q = m - 1;
        while (q >= 0 && ang[ord[q]] > av) { ord[q + 1] = ord[q]; q--; }
        ord[q + 1] = o;
    }
    int o0 = ord[0];
    float fx = px[o0], fy = py[o0];
    float qx[24], qy[24];
#pragma unroll
    for (int m = 0; m < 24; m++) {
        int om = ord[m];
        bool v = (vmask >> om) & 1u;
        qx[m] = v ? px[om] : fx;
        qy[m] = v ? py[om] : fy;
    }
    float ssum = 0.f;
#pragma unroll
    for (int m = 0; m < 24; m++) {
        int m1 = (m + 1) % 24;
        ssum += qx[m] * qy[m1] - qy[m] * qx[m1];
    }
    float area = 0.5f * fabsf(ssum);
    return (n >= 3) ? area : 0.f;
}

// ---------------- K1: decode + min-area polygon + box/corners ----------------
__global__ void k_decode(const float* __restrict__ out3, const float* __restrict__ out4,
                         const float* __restrict__ out5,
                         const float* __restrict__ o1l3, const float* __restrict__ o1l4,
                         const float* __restrict__ o1l5,
                         const float* __restrict__ ofl3, const float* __restrict__ ofl4,
                         const float* __restrict__ ofl5,
                         float* conf, float* cls0, float* cls1, float* xx, float* yy,
                         float* a5, float* rect, float* cor, int* mask) {
    int n = blockIdx.x * blockDim.x + threadIdx.x;
    if (n >= N_DET) return;
    const float *out, *o1, *of;
    int w, idx; float stride;
    if (n < 1024)      { out = out3; o1 = o1l3; of = ofl3; w = 32; idx = n;        stride = 4.f; }
    else if (n < 1280) { out = out4; o1 = o1l4; of = ofl4; w = 16; idx = n - 1024; stride = 8.f; }
    else               { out = out5; o1 = o1l5; of = ofl5; w = 8;  idx = n - 1280; stride = 16.f; }
    int hw = w * w;
    int row = idx / w, col = idx % w;
    float cf = out[0 * hw + idx];
    float c0 = out[1 * hw + idx];
    float c1 = out[2 * hw + idx];
    float x  = out[3 * hw + idx] * stride + stride * (float)col;
    float y  = out[4 * hw + idx] * stride + stride * (float)row;

    float Pa[9], Pb[9];
    float minb = INFINITY, maxb = -INFINITY, mina = INFINITY, maxa = -INFINITY;
#pragma unroll
    for (int k = 0; k < 9; k++) {
        float a = of[(2 * k) * hw + idx]     + o1[(2 * k) * hw + idx]     + y; // even = y-coord
        float b = of[(2 * k + 1) * hw + idx] + o1[(2 * k + 1) * hw + idx] + x; // odd  = x-coord
        Pa[k] = a; Pb[k] = b;
        mina = fminf(mina, a); maxa = fmaxf(maxa, a);
        minb = fminf(minb, b); maxb = fmaxf(maxb, b);
    }
    float area = (maxb - minb) * (maxa - mina) / 40.0f;   // (xs range)*(ys range)/40
    float sg = 1.0f / (1.0f + expf(-area));
    int m = (cf > 0.7f * sg) ? 1 : 0;

    // min-area over 36 direction pairs, first-occurrence argmin
    float best = INFINITY, bc = 0.f, bs = 0.f;
    float bumin = 0.f, bumax = 0.f, bvmin = 0.f, bvmax = 0.f;
    for (int i = 0; i < 9; i++) {
        for (int j = i + 1; j < 9; j++) {
            float d0 = Pa[j] - Pa[i], d1 = Pb[j] - Pb[i];
            float nr = sqrtf(d0 * d0 + d1 * d1 + 1e-12f);
            float c = d0 / nr, s = d1 / nr;
            float umin = INFINITY, umax = -INFINITY, vmin = INFINITY, vmax = -INFINITY;
#pragma unroll
            for (int k = 0; k < 9; k++) {
                float u =  Pa[k] * c + Pb[k] * s;
                float v = -Pa[k] * s + Pb[k] * c;
                umin = fminf(umin, u); umax = fmaxf(umax, u);
                vmin = fminf(vmin, v); vmax = fmaxf(vmax, v);
            }
            float ar = (umax - umin) * (vmax - vmin);
            if (ar < best) { best = ar; bc = c; bs = s;
                             bumin = umin; bumax = umax; bvmin = vmin; bvmax = vmax; }
        }
    }
    float cu[4] = {bumin, bumax, bumax, bumin};
    float cv[4] = {bvmin, bvmin, bvmax, bvmax};
    float r8[8];
#pragma unroll
    for (int k = 0; k < 4; k++) {
        r8[2 * k]     = cu[k] * bc - cv[k] * bs;
        r8[2 * k + 1] = cu[k] * bs + cv[k] * bc;
    }
    float w5 = sqrtf((r8[0] - r8[2]) * (r8[0] - r8[2]) + (r8[1] - r8[3]) * (r8[1] - r8[3]));
    float h5 = sqrtf((r8[4] - r8[2]) * (r8[4] - r8[2]) + (r8[5] - r8[3]) * (r8[5] - r8[3]));
    float cx = (r8[1] + r8[3] + r8[5] + r8[7]) * 0.25f;
    float cy = (r8[0] + r8[2] + r8[4] + r8[6]) * 0.25f;
    float ang = atanf((r8[0] - r8[2]) / (r8[1] - r8[3]));
    float cs = cosf(ang), sn = sinf(ang);
    const float lxs[4] = {-0.5f, 0.5f, 0.5f, -0.5f};
    const float lys[4] = {-0.5f, -0.5f, 0.5f, 0.5f};
#pragma unroll
    for (int k = 0; k < 4; k++) {
        cor[n * 8 + 2 * k]     = cx + lxs[k] * w5 * cs - lys[k] * h5 * sn;
        cor[n * 8 + 2 * k + 1] = cy + lxs[k] * w5 * sn + lys[k] * h5 * cs;
    }
#pragma unroll
    for (int k = 0; k < 8; k++) rect[n * 8 + k] = r8[k];
    conf[n] = cf; cls0[n] = c0; cls1[n] = c1;
    xx[n] = x; yy[n] = y; a5[n] = w5 * h5; mask[n] = m;
}

// ---------------- K2: descending stable order + mask bits ----------------
__global__ void k_order(const float* __restrict__ conf, const int* __restrict__ mask,
                        int* order, unsigned long long* mbits) {
    int i = blockIdx.x * 64 + threadIdx.x;   // grid = 21 blocks x 64 threads
    bool mi = mask[i] != 0;
    unsigned long long b = __ballot(mi);
    if (threadIdx.x == 0) mbits[blockIdx.x] = b;
    float ki = mi ? conf[i] : -INFINITY;
    int rank = 0;
    for (int j = 0; j < N_DET; j++) {
        float kj = mask[j] ? conf[j] : -INFINITY;
        rank += (kj > ki) || (kj == ki && j > i);  // reversed-stable tie-break
    }
    order[rank] = i;
}

// ---------------- K3: pairwise suppression bit-matrix ----------------
// wave per (row i, 64-bit word wj); only mask[i] && mask[j] pairs matter.
__global__ void k_pairs(const float* __restrict__ rect, const float* __restrict__ cor,
                        const float* __restrict__ a5,
                        const float* __restrict__ xx, const float* __restrict__ yy,
                        const int* __restrict__ mask, unsigned long long* __restrict__ S) {
    int gw   = (blockIdx.x * blockDim.x + threadIdx.x) >> 6;
    int lane = threadIdx.x & 63;
    int i  = gw / NW;
    int wj = gw - i * NW;
    if (i >= N_DET) return;
    bool bit = false;
    if (mask[i]) {
        int j = wj * 64 + lane;              // j < N_DET always (NW*64 == N_DET)
        if (mask[j]) {
            // inside test: quads = rect (coords (y,x)), point = (y_j, x_j)
            float qx[4], qy[4];
#pragma unroll
            for (int k = 0; k < 4; k++) { qx[k] = rect[i * 8 + 2 * k]; qy[k] = rect[i * 8 + 2 * k + 1]; }
            bool inside = pt_in_quad4(qx, qy, yy[j], xx[j]);
            float Axr[4], Ayr[4], Bxr[4], Byr[4];
#pragma unroll
            for (int k = 0; k < 4; k++) {
                Axr[k] = cor[i * 8 + 2 * k]; Ayr[k] = cor[i * 8 + 2 * k + 1];
                Bxr[k] = cor[j * 8 + 2 * k]; Byr[k] = cor[j * 8 + 2 * k + 1];
            }
            float inter = quad_inter_area(Axr, Ayr, Bxr, Byr);
            float iou = inter / (a5[i] + a5[j] - inter + 1e-9f);
            bit = inside || (iou >= 0.2f);
        }
    }
    unsigned long long b = __ballot(bit);
    if (lane == 0) S[i * NW + wj] = b;
}

// ---------------- K4: serial scan (wave 0) + outputs ----------------
__global__ __launch_bounds__(1024) void k_scan_out(
    const float* __restrict__ cls0, const float* __restrict__ cls1,
    const float* __restrict__ xx, const float* __restrict__ yy,
    const float* __restrict__ rect,
    const int* __restrict__ order, const unsigned long long* __restrict__ mbits,
    const unsigned long long* __restrict__ S, float* __restrict__ out) {
    __shared__ int order_s[N_DET];
    __shared__ unsigned long long keep_s[NW];
    __shared__ int cnt_s[2];
    int tid = threadIdx.x;
    for (int n = tid; n < N_DET; n += 1024) order_s[n] = order[n];
    if (tid == 0) { cnt_s[0] = 0; cnt_s[1] = 0; }
    __syncthreads();

    if (tid < 64) {
        int lane = tid;
        unsigned long long sup = (lane < NW) ? ~mbits[lane] : 0ull;  // suppressed = !conf_mask
        unsigned long long kp = 0ull;
        for (int it = 0; it < N_DET; it++) {
            int i  = order_s[it];
            int wi = i >> 6, bi = i & 63;
            unsigned long long wv = __shfl(sup, wi, 64);
            bool active = !((wv >> bi) & 1ull);
            if (active) {
                if (lane == wi) kp |= 1ull << bi;
                if (lane < NW) sup |= S[i * NW + lane];
            }
        }
        if (lane < NW) keep_s[lane] = kp;
    }
    __syncthreads();

    int c0 = 0, c1 = 0;
    for (int n = tid; n < N_DET; n += 1024) {
        bool kp = (keep_s[n >> 6] >> (n & 63)) & 1ull;
        float a = cls0[n], b = cls1[n];
        float mxc = fmaxf(a, b);
        bool m0 = kp && (a == mxc);
        bool m1 = kp && (b == mxc);
        float x = xx[n], y = yy[n];
        out[2 + 0 * N_DET * 2 + n * 2 + 0] = m0 ? x : 0.f;
        out[2 + 0 * N_DET * 2 + n * 2 + 1] = m0 ? y : 0.f;
        out[2 + 1 * N_DET * 2 + n * 2 + 0] = m1 ? x : 0.f;
        out[2 + 1 * N_DET * 2 + n * 2 + 1] = m1 ? y : 0.f;
        float kf = kp ? 1.f : 0.f;
#pragma unroll
        for (int k = 0; k < 8; k++)
            out[2 + 2 * N_DET * 2 + n * 8 + k] = rect[n * 8 + k] * kf;
        c0 += m0 ? 1 : 0;
        c1 += m1 ? 1 : 0;
    }
    if (c0) atomicAdd(&cnt_s[0], c0);
    if (c1) atomicAdd(&cnt_s[1], c1);
    __syncthreads();
    if (tid == 0) { out[0] = (float)cnt_s[0]; out[1] = (float)cnt_s[1]; }
}

// ---------------- launch ----------------
extern "C" void kernel_launch(void* const* d_in, const int* in_sizes, int n_in,
                              void* d_out, int out_size, void* d_ws, size_t ws_size,
                              hipStream_t stream) {
    const float* out3 = (const float*)d_in[0];
    const float* out4 = (const float*)d_in[1];
    const float* out5 = (const float*)d_in[2];
    const float* o1l3 = (const float*)d_in[3];
    const float* o1l4 = (const float*)d_in[4];
    const float* o1l5 = (const float*)d_in[5];
    const float* ofl3 = (const float*)d_in[6];
    const float* ofl4 = (const float*)d_in[7];
    const float* ofl5 = (const float*)d_in[8];
    float* out = (float*)d_out;

    const int N = N_DET;
    float* wsf  = (float*)d_ws;
    float* conf = wsf;
    float* cls0 = conf + N;
    float* cls1 = cls0 + N;
    float* xx   = cls1 + N;
    float* yy   = xx + N;
    float* a5   = yy + N;
    float* rect = a5 + N;           // 8N
    float* cor  = rect + 8 * N;     // 8N
    int* mask   = (int*)(cor + 8 * N);   // N
    int* order  = mask + N;              // N
    unsigned long long* mbits = (unsigned long long*)(order + N);  // 21 (8B-aligned: 24N*4 bytes)
    unsigned long long* S     = mbits + NW;                        // N*21

    k_decode<<<(N + 255) / 256, 256, 0, stream>>>(out3, out4, out5, o1l3, o1l4, o1l5,
                                                  ofl3, ofl4, ofl5,
                                                  conf, cls0, cls1, xx, yy, a5, rect, cor, mask);
    k_order<<<NW, 64, 0, stream>>>(conf, mask, order, mbits);
    k_pairs<<<(N * NW * 64) / 256, 256, 0, stream>>>(rect, cor, a5, xx, yy, mask, S);
    k_scan_out<<<1, 1024, 0, stream>>>(cls0, cls1, xx, yy, rect, order, mbits, S, out);
}

// Round 2
// 256.261 us; speedup vs baseline: 2.0907x; 2.0907x over previous
//
#include <hip/hip_runtime.h>
#include <math.h>

#define N_DET 1344
#define NW 21        // N_DET / 64
#define ROWS_LDS 344 // S2 rows staged in LDS for the scan (344*21*8 = 57,792 B)

// ---------------- device helpers ----------------

__device__ __forceinline__ bool pt_in_quad4(const float* qx, const float* qy,
                                            float px, float py) {
    bool allp = true, alln = true;
#pragma unroll
    for (int k = 0; k < 4; k++) {
        int k1 = (k + 1) & 3;
        float ex = qx[k1] - qx[k], ey = qy[k1] - qy[k];
        float rx = px - qx[k],     ry = py - qy[k];
        float cr = ex * ry - ey * rx;
        allp = allp && (cr >= 0.f);
        alln = alln && (cr <= 0.f);
    }
    return allp || alln;
}

// Intersection area of convex quads, fp-order-matched to the JAX reference.
// Register-only: stable angle sort done as a bitonic network on 32 u64 keys
// (ordered-float(angle) << 6 | idx  — embedded idx == stable tie-break),
// carrying the (x,y) coordinates through the network (no dynamic indexing).
__device__ float quad_inter_area(const float* Ax, const float* Ay,
                                 const float* Bx, const float* By) {
    float px[24], py[24];
    unsigned vmask = 0;
    int n = 0;
#pragma unroll
    for (int k = 0; k < 4; k++) {         // A corners, valid if inside B
        px[k] = Ax[k]; py[k] = Ay[k];
        if (pt_in_quad4(Bx, By, Ax[k], Ay[k])) { vmask |= 1u << k; n++; }
    }
#pragma unroll
    for (int k = 0; k < 4; k++) {         // B corners, valid if inside A
        px[4 + k] = Bx[k]; py[4 + k] = By[k];
        if (pt_in_quad4(Ax, Ay, Bx[k], By[k])) { vmask |= 1u << (4 + k); n++; }
    }
#pragma unroll
    for (int k = 0; k < 4; k++) {
        int k1 = (k + 1) & 3;
        float rax = Ax[k1] - Ax[k], ray = Ay[k1] - Ay[k];
#pragma unroll
        for (int l = 0; l < 4; l++) {
            int l1 = (l + 1) & 3;
            float rbx = Bx[l1] - Bx[l], rby = By[l1] - By[l];
            float qpx = Bx[l] - Ax[k],  qpy = By[l] - Ay[k];
            float den = rax * rby - ray * rbx;
            float ad  = fabsf(den);
            float dsafe = (ad < 1e-9f) ? 1e-9f : den;
            float t = (qpx * rby - qpy * rbx) / dsafe;
            float u = (qpx * ray - qpy * rax) / dsafe;
            bool ok = (ad > 1e-9f) && t >= 0.f && t <= 1.f && u >= 0.f && u <= 1.f;
            int id = 8 + k * 4 + l;
            px[id] = Ax[k] + t * rax;
            py[id] = Ay[k] + t * ray;
            if (ok) { vmask |= 1u << id; n++; }
        }
    }
    float cx = 0.f, cy = 0.f;
#pragma unroll
    for (int m = 0; m < 24; m++)
        if ((vmask >> m) & 1u) { cx += px[m]; cy += py[m]; }
    int mx = (n < 1) ? 1 : n;
    cx = cx / (float)mx;
    cy = cy / (float)mx;

    unsigned long long key[32];
    float sx[32], sy[32];
#pragma unroll
    for (int m = 0; m < 24; m++) {
        float rx = px[m] - cx, ry = py[m] - cy;
        float a = ((vmask >> m) & 1u) ? atan2f(ry, rx) : 1e9f;
        unsigned u = __float_as_uint(a);
        u = (u & 0x80000000u) ? ~u : (u | 0x80000000u);
        key[m] = (((unsigned long long)u) << 6) | (unsigned)m;
        sx[m] = rx; sy[m] = ry;
    }
#pragma unroll
    for (int m = 24; m < 32; m++) { key[m] = ~0ull; sx[m] = 0.f; sy[m] = 0.f; }

    // bitonic sort, ascending key (keys are all distinct -> order unique)
#pragma unroll
    for (int k = 2; k <= 32; k <<= 1) {
#pragma unroll
        for (int j = k >> 1; j > 0; j >>= 1) {
#pragma unroll
            for (int t = 0; t < 32; t++) {
                int l = t ^ j;
                if (l > t) {
                    bool up = ((t & k) == 0);
                    bool sw = up ? (key[t] > key[l]) : (key[t] < key[l]);
                    if (sw) {
                        unsigned long long tk = key[t]; key[t] = key[l]; key[l] = tk;
                        float tx = sx[t]; sx[t] = sx[l]; sx[l] = tx;
                        float ty = sy[t]; sy[t] = sy[l]; sy[l] = ty;
                    }
                }
            }
        }
    }

    unsigned ut = __float_as_uint(1e9f) | 0x80000000u;
    unsigned long long kt = ((unsigned long long)ut) << 6;   // keys < kt are valid
    float fx = sx[0], fy = sy[0];
    float qx2[24], qy2[24];
#pragma unroll
    for (int m = 0; m < 24; m++) {
        bool v = key[m] < kt;
        qx2[m] = v ? sx[m] : fx;
        qy2[m] = v ? sy[m] : fy;
    }
    float ssum = 0.f;
#pragma unroll
    for (int m = 0; m < 24; m++) {
        int m1 = (m + 1) % 24;
        ssum += qx2[m] * qy2[m1] - qy2[m] * qx2[m1];
    }
    float area = 0.5f * fabsf(ssum);
    return (n >= 3) ? area : 0.f;
}

// ---------------- K1: decode + min-area polygon + box/corners ----------------
__global__ void k_decode(const float* __restrict__ out3, const float* __restrict__ out4,
                         const float* __restrict__ out5,
                         const float* __restrict__ o1l3, const float* __restrict__ o1l4,
                         const float* __restrict__ o1l5,
                         const float* __restrict__ ofl3, const float* __restrict__ ofl4,
                         const float* __restrict__ ofl5,
                         float* conf, float* cls0, float* cls1, float* xx, float* yy,
                         float* a5, float* rect, float* cor, int* mask) {
    int n = blockIdx.x * blockDim.x + threadIdx.x;
    if (n >= N_DET) return;
    const float *out, *o1, *of;
    int w, idx; float stride;
    if (n < 1024)      { out = out3; o1 = o1l3; of = ofl3; w = 32; idx = n;        stride = 4.f; }
    else if (n < 1280) { out = out4; o1 = o1l4; of = ofl4; w = 16; idx = n - 1024; stride = 8.f; }
    else               { out = out5; o1 = o1l5; of = ofl5; w = 8;  idx = n - 1280; stride = 16.f; }
    int hw = w * w;
    int row = idx / w, col = idx % w;
    float cf = out[0 * hw + idx];
    float c0 = out[1 * hw + idx];
    float c1 = out[2 * hw + idx];
    float x  = out[3 * hw + idx] * stride + stride * (float)col;
    float y  = out[4 * hw + idx] * stride + stride * (float)row;

    float Pa[9], Pb[9];
    float minb = INFINITY, maxb = -INFINITY, mina = INFINITY, maxa = -INFINITY;
#pragma unroll
    for (int k = 0; k < 9; k++) {
        float a = of[(2 * k) * hw + idx]     + o1[(2 * k) * hw + idx]     + y; // even = y
        float b = of[(2 * k + 1) * hw + idx] + o1[(2 * k + 1) * hw + idx] + x; // odd  = x
        Pa[k] = a; Pb[k] = b;
        mina = fminf(mina, a); maxa = fmaxf(maxa, a);
        minb = fminf(minb, b); maxb = fmaxf(maxb, b);
    }
    float area = (maxb - minb) * (maxa - mina) / 40.0f;
    float sg = 1.0f / (1.0f + expf(-area));
    int m = (cf > 0.7f * sg) ? 1 : 0;

    float best = INFINITY, bc = 0.f, bs = 0.f;
    float bumin = 0.f, bumax = 0.f, bvmin = 0.f, bvmax = 0.f;
#pragma unroll
    for (int i = 0; i < 9; i++) {
#pragma unroll
        for (int j = i + 1; j < 9; j++) {
            float d0 = Pa[j] - Pa[i], d1 = Pb[j] - Pb[i];
            float nr = sqrtf(d0 * d0 + d1 * d1 + 1e-12f);
            float c = d0 / nr, s = d1 / nr;
            float umin = INFINITY, umax = -INFINITY, vmin = INFINITY, vmax = -INFINITY;
#pragma unroll
            for (int k = 0; k < 9; k++) {
                float u =  Pa[k] * c + Pb[k] * s;
                float v = -Pa[k] * s + Pb[k] * c;
                umin = fminf(umin, u); umax = fmaxf(umax, u);
                vmin = fminf(vmin, v); vmax = fmaxf(vmax, v);
            }
            float ar = (umax - umin) * (vmax - vmin);
            if (ar < best) { best = ar; bc = c; bs = s;
                             bumin = umin; bumax = umax; bvmin = vmin; bvmax = vmax; }
        }
    }
    float cu[4] = {bumin, bumax, bumax, bumin};
    float cv[4] = {bvmin, bvmin, bvmax, bvmax};
    float r8[8];
#pragma unroll
    for (int k = 0; k < 4; k++) {
        r8[2 * k]     = cu[k] * bc - cv[k] * bs;
        r8[2 * k + 1] = cu[k] * bs + cv[k] * bc;
    }
    float w5 = sqrtf((r8[0] - r8[2]) * (r8[0] - r8[2]) + (r8[1] - r8[3]) * (r8[1] - r8[3]));
    float h5 = sqrtf((r8[4] - r8[2]) * (r8[4] - r8[2]) + (r8[5] - r8[3]) * (r8[5] - r8[3]));
    float cx = (r8[1] + r8[3] + r8[5] + r8[7]) * 0.25f;
    float cy = (r8[0] + r8[2] + r8[4] + r8[6]) * 0.25f;
    float ang = atanf((r8[0] - r8[2]) / (r8[1] - r8[3]));
    float cs = cosf(ang), sn = sinf(ang);
    const float lxs[4] = {-0.5f, 0.5f, 0.5f, -0.5f};
    const float lys[4] = {-0.5f, -0.5f, 0.5f, 0.5f};
#pragma unroll
    for (int k = 0; k < 4; k++) {
        cor[n * 8 + 2 * k]     = cx + lxs[k] * w5 * cs - lys[k] * h5 * sn;
        cor[n * 8 + 2 * k + 1] = cy + lxs[k] * w5 * sn + lys[k] * h5 * cs;
    }
#pragma unroll
    for (int k = 0; k < 8; k++) rect[n * 8 + k] = r8[k];
    conf[n] = cf; cls0[n] = c0; cls1[n] = c1;
    xx[n] = x; yy[n] = y; a5[n] = w5 * h5; mask[n] = m;
}

// ---------------- K2: descending stable order + masked count M ----------------
__global__ __launch_bounds__(256) void k_order(const float* __restrict__ conf,
                                               const int* __restrict__ mask,
                                               int* order, int* Mcnt) {
    __shared__ float keys[N_DET];
    __shared__ int mcount;
    int tid = threadIdx.x;
    int n = blockIdx.x * 256 + tid;
    for (int t = tid; t < N_DET; t += 256)
        keys[t] = mask[t] ? conf[t] : -INFINITY;
    if (tid == 0) mcount = 0;
    __syncthreads();
    if (n < N_DET) {
        float ki = keys[n];
        int rank = 0;
        for (int j = 0; j < N_DET; j++) {
            float kj = keys[j];
            rank += (kj > ki) || (kj == ki && j > n);  // reversed-stable tie-break
        }
        order[rank] = n;
    }
    if (blockIdx.x == 0) {
        int c = 0;
        for (int t = tid; t < N_DET; t += 256)
            c += (keys[t] != -INFINITY) ? 1 : 0;
        atomicAdd(&mcount, c);
        __syncthreads();
        if (tid == 0) *Mcnt = mcount;
    }
}

// ---------------- K3: compacted pairwise suppression bit-matrix ----------------
// wave per (compacted row p, 64-bit column word w); rows/cols are masked-only,
// sorted by descending conf. S2[p][w] bit b set => candidate q=w*64+b suppressed by p.
__global__ __launch_bounds__(256, 1) void k_pairs(
        const float* __restrict__ rect, const float* __restrict__ cor,
        const float* __restrict__ a5,
        const float* __restrict__ xx, const float* __restrict__ yy,
        const int* __restrict__ order, const int* __restrict__ Mcnt,
        unsigned long long* __restrict__ S2) {
    int gw   = (blockIdx.x * 256 + threadIdx.x) >> 6;
    int lane = threadIdx.x & 63;
    int p = gw / NW;
    int w = gw - p * NW;
    int M = *Mcnt;
    if (p >= M) return;
    int i = order[p];
    int q = w * 64 + lane;
    bool valid = q < M;
    int j = valid ? order[q] : i;

    float qxr[4], qyr[4];
#pragma unroll
    for (int k = 0; k < 4; k++) { qxr[k] = rect[i * 8 + 2 * k]; qyr[k] = rect[i * 8 + 2 * k + 1]; }
    bool inside = pt_in_quad4(qxr, qyr, yy[j], xx[j]);

    float Axr[4], Ayr[4], Bxr[4], Byr[4];
#pragma unroll
    for (int k = 0; k < 4; k++) {
        Axr[k] = cor[i * 8 + 2 * k]; Ayr[k] = cor[i * 8 + 2 * k + 1];
        Bxr[k] = cor[j * 8 + 2 * k]; Byr[k] = cor[j * 8 + 2 * k + 1];
    }
    float inter = quad_inter_area(Axr, Ayr, Bxr, Byr);
    float iou = inter / (a5[i] + a5[j] - inter + 1e-9f);
    bool bit = valid && (inside || iou >= 0.2f);
    unsigned long long bb = __ballot(bit);
    if (lane == 0) S2[p * NW + w] = bb;
}

// ---------------- K4: remaining-bitmask scan (K iterations) + outputs ----------------
__global__ __launch_bounds__(1024) void k_scan_out(
    const float* __restrict__ cls0, const float* __restrict__ cls1,
    const float* __restrict__ xx, const float* __restrict__ yy,
    const float* __restrict__ rect,
    const int* __restrict__ order, const int* __restrict__ Mcnt,
    const unsigned long long* __restrict__ S2, float* __restrict__ out) {
    __shared__ int order_s[N_DET];
    __shared__ unsigned long long S2s[ROWS_LDS * NW];
    __shared__ unsigned long long keep_s[NW];
    __shared__ int cnt_s[2];
    int tid = threadIdx.x;
    int M = *Mcnt;
    for (int t = tid; t < N_DET; t += 1024) order_s[t] = order[t];
    int rows = (M < ROWS_LDS) ? M : ROWS_LDS;
    for (int t = tid; t < rows * NW; t += 1024) S2s[t] = S2[t];
    if (tid < NW) keep_s[tid] = 0ull;
    if (tid < 2) cnt_s[tid] = 0;
    __syncthreads();

    if (tid < 64) {
        int lane = tid;
        int lo = lane * 64;
        unsigned long long rem = 0ull;   // bits of still-alive candidates (compacted)
        if (M > lo) rem = (M - lo >= 64) ? ~0ull : ((1ull << (M - lo)) - 1ull);
        unsigned long long kp = 0ull;    // lane l accumulates keep bits of orig-word l
        for (int guard = 0; guard < N_DET; guard++) {
            unsigned long long vote = __ballot(rem != 0ull);
            if (vote == 0ull) break;
            int w = __ffsll(vote) - 1;               // first word with a live bit
            unsigned long long wd = __shfl(rem, w, 64);
            int b = __ffsll(wd) - 1;
            int p = w * 64 + b;                      // next kept candidate
            int i = order_s[p];
            if (lane == (i >> 6)) kp |= 1ull << (i & 63);
            unsigned long long row = 0ull;
            if (lane < NW)
                row = (p < ROWS_LDS) ? S2s[p * NW + lane] : S2[p * NW + lane];
            rem &= ~row;
            if (lane == w) rem &= ~(1ull << b);      // self always cleared
        }
        if (lane < NW) keep_s[lane] = kp;
    }
    __syncthreads();

    int c0 = 0, c1 = 0;
    for (int n = tid; n < N_DET; n += 1024) {
        bool kp = (keep_s[n >> 6] >> (n & 63)) & 1ull;
        float a = cls0[n], b = cls1[n];
        float mxc = fmaxf(a, b);
        bool m0 = kp && (a == mxc);
        bool m1 = kp && (b == mxc);
        float x = xx[n], y = yy[n];
        out[2 + 0 * N_DET * 2 + n * 2 + 0] = m0 ? x : 0.f;
        out[2 + 0 * N_DET * 2 + n * 2 + 1] = m0 ? y : 0.f;
        out[2 + 1 * N_DET * 2 + n * 2 + 0] = m1 ? x : 0.f;
        out[2 + 1 * N_DET * 2 + n * 2 + 1] = m1 ? y : 0.f;
        float kf = kp ? 1.f : 0.f;
#pragma unroll
        for (int k = 0; k < 8; k++)
            out[2 + 2 * N_DET * 2 + n * 8 + k] = rect[n * 8 + k] * kf;
        c0 += m0 ? 1 : 0;
        c1 += m1 ? 1 : 0;
    }
    if (c0) atomicAdd(&cnt_s[0], c0);
    if (c1) atomicAdd(&cnt_s[1], c1);
    __syncthreads();
    if (tid == 0) { out[0] = (float)cnt_s[0]; out[1] = (float)cnt_s[1]; }
}

// ---------------- launch ----------------
extern "C" void kernel_launch(void* const* d_in, const int* in_sizes, int n_in,
                              void* d_out, int out_size, void* d_ws, size_t ws_size,
                              hipStream_t stream) {
    const float* out3 = (const float*)d_in[0];
    const float* out4 = (const float*)d_in[1];
    const float* out5 = (const float*)d_in[2];
    const float* o1l3 = (const float*)d_in[3];
    const float* o1l4 = (const float*)d_in[4];
    const float* o1l5 = (const float*)d_in[5];
    const float* ofl3 = (const float*)d_in[6];
    const float* ofl4 = (const float*)d_in[7];
    const float* ofl5 = (const float*)d_in[8];
    float* out = (float*)d_out;

    const int N = N_DET;
    float* wsf  = (float*)d_ws;
    float* conf = wsf;
    float* cls0 = conf + N;
    float* cls1 = cls0 + N;
    float* xx   = cls1 + N;
    float* yy   = xx + N;
    float* a5   = yy + N;
    float* rect = a5 + N;            // 8N
    float* cor  = rect + 8 * N;      // 8N
    int* mask   = (int*)(cor + 8 * N);   // N
    int* order  = mask + N;              // N
    int* Mcnt   = order + N;             // 2 ints (8B pad)
    unsigned long long* S2 = (unsigned long long*)(Mcnt + 2);  // N*NW u64

    k_decode<<<(N + 255) / 256, 256, 0, stream>>>(out3, out4, out5, o1l3, o1l4, o1l5,
                                                  ofl3, ofl4, ofl5,
                                                  conf, cls0, cls1, xx, yy, a5, rect, cor, mask);
    k_order<<<(N + 255) / 256, 256, 0, stream>>>(conf, mask, order, Mcnt);
    k_pairs<<<(N * NW) / 4, 256, 0, stream>>>(rect, cor, a5, xx, yy, order, Mcnt, S2);
    k_scan_out<<<1, 1024, 0, stream>>>(cls0, cls1, xx, yy, rect, order, Mcnt, S2, out);
}

// Round 3
// 139.166 us; speedup vs baseline: 3.8499x; 1.8414x over previous
//
#include <hip/hip_runtime.h>
#include <math.h>

#define N_DET 1344
#define NW 21        // max column words (N_DET/64)
#define MW_MAX 8     // Jacobi fast path supports M <= 512
#define T2S 9        // padded T2 row stride (u64) — breaks LDS bank conflicts
#define PAIR_CAP 40000

// ---------------- device helpers ----------------

__device__ __forceinline__ bool pt_in_quad4(const float* qx, const float* qy,
                                            float px, float py) {
    bool allp = true, alln = true;
#pragma unroll
    for (int k = 0; k < 4; k++) {
        int k1 = (k + 1) & 3;
        float ex = qx[k1] - qx[k], ey = qy[k1] - qy[k];
        float rx = px - qx[k],     ry = py - qy[k];
        float cr = ex * ry - ey * rx;
        allp = allp && (cr >= 0.f);
        alln = alln && (cr <= 0.f);
    }
    return allp || alln;
}

// Exact fp-order-matched intersection area (register-only bitonic sort).
__device__ float quad_inter_area(const float* Ax, const float* Ay,
                                 const float* Bx, const float* By) {
    float px[24], py[24];
    unsigned vmask = 0;
    int n = 0;
#pragma unroll
    for (int k = 0; k < 4; k++) {
        px[k] = Ax[k]; py[k] = Ay[k];
        if (pt_in_quad4(Bx, By, Ax[k], Ay[k])) { vmask |= 1u << k; n++; }
    }
#pragma unroll
    for (int k = 0; k < 4; k++) {
        px[4 + k] = Bx[k]; py[4 + k] = By[k];
        if (pt_in_quad4(Ax, Ay, Bx[k], By[k])) { vmask |= 1u << (4 + k); n++; }
    }
#pragma unroll
    for (int k = 0; k < 4; k++) {
        int k1 = (k + 1) & 3;
        float rax = Ax[k1] - Ax[k], ray = Ay[k1] - Ay[k];
#pragma unroll
        for (int l = 0; l < 4; l++) {
            int l1 = (l + 1) & 3;
            float rbx = Bx[l1] - Bx[l], rby = By[l1] - By[l];
            float qpx = Bx[l] - Ax[k],  qpy = By[l] - Ay[k];
            float den = rax * rby - ray * rbx;
            float ad  = fabsf(den);
            float dsafe = (ad < 1e-9f) ? 1e-9f : den;
            float t = (qpx * rby - qpy * rbx) / dsafe;
            float u = (qpx * ray - qpy * rax) / dsafe;
            bool ok = (ad > 1e-9f) && t >= 0.f && t <= 1.f && u >= 0.f && u <= 1.f;
            int id = 8 + k * 4 + l;
            px[id] = Ax[k] + t * rax;
            py[id] = Ay[k] + t * ray;
            if (ok) { vmask |= 1u << id; n++; }
        }
    }
    float cx = 0.f, cy = 0.f;
#pragma unroll
    for (int m = 0; m < 24; m++)
        if ((vmask >> m) & 1u) { cx += px[m]; cy += py[m]; }
    int mx = (n < 1) ? 1 : n;
    cx = cx / (float)mx;
    cy = cy / (float)mx;

    unsigned long long key[32];
    float sx[32], sy[32];
#pragma unroll
    for (int m = 0; m < 24; m++) {
        float rx = px[m] - cx, ry = py[m] - cy;
        float a = ((vmask >> m) & 1u) ? atan2f(ry, rx) : 1e9f;
        unsigned u = __float_as_uint(a);
        u = (u & 0x80000000u) ? ~u : (u | 0x80000000u);
        key[m] = (((unsigned long long)u) << 6) | (unsigned)m;
        sx[m] = rx; sy[m] = ry;
    }
#pragma unroll
    for (int m = 24; m < 32; m++) { key[m] = ~0ull; sx[m] = 0.f; sy[m] = 0.f; }

#pragma unroll
    for (int k = 2; k <= 32; k <<= 1) {
#pragma unroll
        for (int j = k >> 1; j > 0; j >>= 1) {
#pragma unroll
            for (int t = 0; t < 32; t++) {
                int l = t ^ j;
                if (l > t) {
                    bool up = ((t & k) == 0);
                    bool sw = up ? (key[t] > key[l]) : (key[t] < key[l]);
                    if (sw) {
                        unsigned long long tk = key[t]; key[t] = key[l]; key[l] = tk;
                        float tx = sx[t]; sx[t] = sx[l]; sx[l] = tx;
                        float ty = sy[t]; sy[t] = sy[l]; sy[l] = ty;
                    }
                }
            }
        }
    }

    unsigned ut = __float_as_uint(1e9f) | 0x80000000u;
    unsigned long long kt = ((unsigned long long)ut) << 6;
    float fx = sx[0], fy = sy[0];
    float qx2[24], qy2[24];
#pragma unroll
    for (int m = 0; m < 24; m++) {
        bool v = key[m] < kt;
        qx2[m] = v ? sx[m] : fx;
        qy2[m] = v ? sy[m] : fy;
    }
    float ssum = 0.f;
#pragma unroll
    for (int m = 0; m < 24; m++) {
        int m1 = (m + 1) % 24;
        ssum += qx2[m] * qy2[m1] - qy2[m] * qx2[m1];
    }
    float area = 0.5f * fabsf(ssum);
    return (n >= 3) ? area : 0.f;
}

__device__ bool iou_suppress(const float* __restrict__ cor, const float* __restrict__ a5,
                             int i, int j) {
    float Axr[4], Ayr[4], Bxr[4], Byr[4];
#pragma unroll
    for (int k = 0; k < 4; k++) {
        Axr[k] = cor[i * 8 + 2 * k]; Ayr[k] = cor[i * 8 + 2 * k + 1];
        Bxr[k] = cor[j * 8 + 2 * k]; Byr[k] = cor[j * 8 + 2 * k + 1];
    }
    float inter = quad_inter_area(Axr, Ayr, Bxr, Byr);
    float iou = inter / (a5[i] + a5[j] - inter + 1e-9f);
    return iou >= 0.2f;
}

// ---------------- K1: decode + min-area polygon + box/corners + circles ----------------
__global__ void k_decode(const float* __restrict__ out3, const float* __restrict__ out4,
                         const float* __restrict__ out5,
                         const float* __restrict__ o1l3, const float* __restrict__ o1l4,
                         const float* __restrict__ o1l5,
                         const float* __restrict__ ofl3, const float* __restrict__ ofl4,
                         const float* __restrict__ ofl5,
                         float* conf, float* cls0, float* cls1, float* xx, float* yy,
                         float* a5, float* ccx, float* ccy, float* rr,
                         float* rect, float* cor, int* mask, int* Mcnt, int* pairCnt) {
    int n = blockIdx.x * blockDim.x + threadIdx.x;
    if (n >= N_DET) return;
    if (n == 0) { *Mcnt = 0; *pairCnt = 0; }
    const float *out, *o1, *of;
    int w, idx; float stride;
    if (n < 1024)      { out = out3; o1 = o1l3; of = ofl3; w = 32; idx = n;        stride = 4.f; }
    else if (n < 1280) { out = out4; o1 = o1l4; of = ofl4; w = 16; idx = n - 1024; stride = 8.f; }
    else               { out = out5; o1 = o1l5; of = ofl5; w = 8;  idx = n - 1280; stride = 16.f; }
    int hw = w * w;
    int row = idx / w, col = idx % w;
    float cf = out[0 * hw + idx];
    float c0 = out[1 * hw + idx];
    float c1 = out[2 * hw + idx];
    float x  = out[3 * hw + idx] * stride + stride * (float)col;
    float y  = out[4 * hw + idx] * stride + stride * (float)row;

    float Pa[9], Pb[9];
    float minb = INFINITY, maxb = -INFINITY, mina = INFINITY, maxa = -INFINITY;
#pragma unroll
    for (int k = 0; k < 9; k++) {
        float a = of[(2 * k) * hw + idx]     + o1[(2 * k) * hw + idx]     + y;
        float b = of[(2 * k + 1) * hw + idx] + o1[(2 * k + 1) * hw + idx] + x;
        Pa[k] = a; Pb[k] = b;
        mina = fminf(mina, a); maxa = fmaxf(maxa, a);
        minb = fminf(minb, b); maxb = fmaxf(maxb, b);
    }
    float area = (maxb - minb) * (maxa - mina) / 40.0f;
    float sg = 1.0f / (1.0f + expf(-area));
    int m = (cf > 0.7f * sg) ? 1 : 0;

    float best = INFINITY, bc = 0.f, bs = 0.f;
    float bumin = 0.f, bumax = 0.f, bvmin = 0.f, bvmax = 0.f;
#pragma unroll
    for (int i = 0; i < 9; i++) {
#pragma unroll
        for (int j = i + 1; j < 9; j++) {
            float d0 = Pa[j] - Pa[i], d1 = Pb[j] - Pb[i];
            float nr = sqrtf(d0 * d0 + d1 * d1 + 1e-12f);
            float c = d0 / nr, s = d1 / nr;
            float umin = INFINITY, umax = -INFINITY, vmin = INFINITY, vmax = -INFINITY;
#pragma unroll
            for (int k = 0; k < 9; k++) {
                float u =  Pa[k] * c + Pb[k] * s;
                float v = -Pa[k] * s + Pb[k] * c;
                umin = fminf(umin, u); umax = fmaxf(umax, u);
                vmin = fminf(vmin, v); vmax = fmaxf(vmax, v);
            }
            float ar = (umax - umin) * (vmax - vmin);
            if (ar < best) { best = ar; bc = c; bs = s;
                             bumin = umin; bumax = umax; bvmin = vmin; bvmax = vmax; }
        }
    }
    float cu[4] = {bumin, bumax, bumax, bumin};
    float cv[4] = {bvmin, bvmin, bvmax, bvmax};
    float r8[8];
#pragma unroll
    for (int k = 0; k < 4; k++) {
        r8[2 * k]     = cu[k] * bc - cv[k] * bs;
        r8[2 * k + 1] = cu[k] * bs + cv[k] * bc;
    }
    float w5 = sqrtf((r8[0] - r8[2]) * (r8[0] - r8[2]) + (r8[1] - r8[3]) * (r8[1] - r8[3]));
    float h5 = sqrtf((r8[4] - r8[2]) * (r8[4] - r8[2]) + (r8[5] - r8[3]) * (r8[5] - r8[3]));
    float cx = (r8[1] + r8[3] + r8[5] + r8[7]) * 0.25f;
    float cy = (r8[0] + r8[2] + r8[4] + r8[6]) * 0.25f;
    float ang = atanf((r8[0] - r8[2]) / (r8[1] - r8[3]));
    float cs = cosf(ang), sn = sinf(ang);
    const float lxs[4] = {-0.5f, 0.5f, 0.5f, -0.5f};
    const float lys[4] = {-0.5f, -0.5f, 0.5f, 0.5f};
#pragma unroll
    for (int k = 0; k < 4; k++) {
        cor[n * 8 + 2 * k]     = cx + lxs[k] * w5 * cs - lys[k] * h5 * sn;
        cor[n * 8 + 2 * k + 1] = cy + lxs[k] * w5 * sn + lys[k] * h5 * cs;
    }
#pragma unroll
    for (int k = 0; k < 8; k++) rect[n * 8 + k] = r8[k];
    conf[n] = cf; cls0[n] = c0; cls1[n] = c1;
    xx[n] = x; yy[n] = y; a5[n] = w5 * h5; mask[n] = m;
    ccx[n] = cx; ccy[n] = cy;
    rr[n] = 0.5f * sqrtf(w5 * w5 + h5 * h5);   // circumradius (conservative-filter only)
}

// ---------------- K2: rank per candidate (one 64-lane block each) ----------------
__global__ __launch_bounds__(64) void k_order(const float* __restrict__ conf,
                                              const int* __restrict__ mask,
                                              int* order, int* Mcnt) {
    int b = blockIdx.x;
    int lane = threadIdx.x;
    int mb = mask[b];
    float ki = mb ? conf[b] : -INFINITY;
    int rank = 0;
    for (int j = lane; j < N_DET; j += 64) {
        float kj = mask[j] ? conf[j] : -INFINITY;
        rank += ((kj > ki) || (kj == ki && j > b)) ? 1 : 0;
    }
    for (int off = 32; off; off >>= 1) rank += __shfl_down(rank, off, 64);
    if (lane == 0) {
        order[rank] = b;
        if (mb) atomicAdd(Mcnt, 1);
    }
}

// ---------------- K3a: cheap tests + inside bits + needy-pair compaction ----------------
__global__ __launch_bounds__(256) void k_pairs_a(
        const float* __restrict__ rect, const float* __restrict__ cor,
        const float* __restrict__ a5,
        const float* __restrict__ xx, const float* __restrict__ yy,
        const float* __restrict__ ccx, const float* __restrict__ ccy,
        const float* __restrict__ rr,
        const int* __restrict__ order, const int* __restrict__ Mcnt,
        unsigned long long* __restrict__ S2, unsigned int* __restrict__ pairs,
        int* __restrict__ pairCnt) {
    int gw   = (blockIdx.x * 256 + threadIdx.x) >> 6;
    int lane = threadIdx.x & 63;
    int M = *Mcnt;
    int MW = (M + 63) >> 6;
    int p = gw / NW;
    int w = gw - p * NW;
    if (p >= M || w >= MW) return;
    bool use_list = (MW <= MW_MAX);
    int i = order[p];
    int q = w * 64 + lane;
    bool valid = q < M;
    int j = valid ? order[q] : i;

    float cxi = ccx[i], cyi = ccy[i], ri = rr[i];
    // inside prefilter: point (yy_j, xx_j) vs rect_i; rect center in (even,odd) coords = (cyi, cxi)
    float dy0 = yy[j] - cyi, dx0 = xx[j] - cxi;
    float rin = ri + 0.1f;
    bool inside = false;
    if (dy0 * dy0 + dx0 * dx0 <= rin * rin) {
        float qxr[4], qyr[4];
#pragma unroll
        for (int k = 0; k < 4; k++) { qxr[k] = rect[i * 8 + 2 * k]; qyr[k] = rect[i * 8 + 2 * k + 1]; }
        inside = pt_in_quad4(qxr, qyr, yy[j], xx[j]);
    }
    bool bit = valid && inside;
    unsigned long long bb = __ballot(bit);
    if (lane == 0) S2[p * MW + w] = bb;

    // iou prefilter: circumcircles overlap?
    float ex = cxi - ccx[j], ey = cyi - ccy[j];
    float rs = ri + rr[j] + 0.1f;
    bool iou_pos = valid && (q != p) && !bit && (ex * ex + ey * ey <= rs * rs);
    if (iou_pos) {
        if (use_list) {
            int pos = atomicAdd(pairCnt, 1);
            if (pos < PAIR_CAP) {
                pairs[pos] = ((unsigned)p << 11) | (unsigned)q;
            } else if (iou_suppress(cor, a5, i, j)) {   // overflow: exact inline
                atomicOr(&S2[p * MW + (q >> 6)], 1ull << (q & 63));
            }
        } else if (iou_suppress(cor, a5, i, j)) {       // fallback mode: no list
            atomicOr(&S2[p * MW + (q >> 6)], 1ull << (q & 63));
        }
    }
}

// ---------------- K3b: exact intersection on compacted needy pairs ----------------
__global__ __launch_bounds__(256) void k_pairs_b(
        const float* __restrict__ cor, const float* __restrict__ a5,
        const int* __restrict__ order, const int* __restrict__ Mcnt,
        const int* __restrict__ pairCnt, const unsigned int* __restrict__ pairs,
        unsigned long long* __restrict__ S2) {
    int M = *Mcnt;
    int MW = (M + 63) >> 6;
    if (MW > MW_MAX) return;           // list unused in fallback mode
    int cnt = *pairCnt; if (cnt > PAIR_CAP) cnt = PAIR_CAP;
    int stride = gridDim.x * 256;
    for (int t = blockIdx.x * 256 + threadIdx.x; t < cnt; t += stride) {
        unsigned v = pairs[t];
        int p = (int)(v >> 11), q = (int)(v & 2047u);
        int i = order[p], j = order[q];
        if (iou_suppress(cor, a5, i, j))
            atomicOr(&S2[p * MW + (q >> 6)], 1ull << (q & 63));
    }
}

// ---------------- K4: Jacobi fixed-point NMS + outputs ----------------
__global__ __launch_bounds__(1024) void k_scan_out(
    const float* __restrict__ cls0, const float* __restrict__ cls1,
    const float* __restrict__ xx, const float* __restrict__ yy,
    const float* __restrict__ rect,
    const int* __restrict__ order, const int* __restrict__ Mcnt,
    const unsigned long long* __restrict__ S2, float* __restrict__ out) {
    __shared__ int order_s[N_DET];
    __shared__ unsigned long long T2[512 * T2S];
    __shared__ unsigned long long Kbuf[2][MW_MAX];
    __shared__ unsigned int keep32[(N_DET + 31) / 32];
    __shared__ int changed;
    __shared__ int cnt_s[2];
    int tid = threadIdx.x;
    int lane = tid & 63, wid = tid >> 6;
    int M = *Mcnt;
    int MW = (M + 63) >> 6;
    for (int t = tid; t < N_DET; t += 1024) order_s[t] = order[t];
    for (int t = tid; t < (N_DET + 31) / 32; t += 1024) keep32[t] = 0u;
    if (tid == 0) changed = 0;
    if (tid < 2) cnt_s[tid] = 0;
    __syncthreads();

    int cur = 0;
    if (M > 0 && MW <= MW_MAX) {
        // --- bit-transpose S2 -> T2 (64x64 blocks via ballots) ---
        for (int blk = wid; blk < MW * MW; blk += 16) {
            int wp = blk / MW, wq = blk - wp * MW;
            int pp = wp * 64 + lane;
            unsigned long long x = (pp < M) ? S2[pp * MW + wq] : 0ull;
#pragma unroll
            for (int b = 0; b < 64; b++) {
                unsigned long long bb = __ballot((x >> b) & 1ull);
                if (lane == b) T2[(wq * 64 + b) * T2S + wp] = bb;
            }
        }
        if (tid < MW_MAX) {
            int lo = tid * 64;
            unsigned long long iv = 0ull;
            if (M > lo) iv = (M - lo >= 64) ? ~0ull : ((1ull << (M - lo)) - 1ull);
            Kbuf[0][tid] = iv;
            Kbuf[1][tid] = 0ull;
        }
        __syncthreads();

        // --- Jacobi sweeps: keep[q] = !any(p<q, keep[p] & S[p][q]) ---
        for (int it = 0; it <= M; ++it) {
            bool newk = false;
            if (tid < 512 && tid < M) {
                int q = tid, qw = q >> 6;
                unsigned long long sup = 0ull;
                for (int w = 0; w < qw; ++w) sup |= T2[q * T2S + w] & Kbuf[cur][w];
                unsigned long long pm = (q & 63) ? ((1ull << (q & 63)) - 1ull) : 0ull;
                sup |= T2[q * T2S + qw] & Kbuf[cur][qw] & pm;
                newk = (sup == 0ull);
            }
            unsigned long long bb = __ballot(newk);
            if (wid < MW_MAX && lane == 0) {
                if (bb != Kbuf[cur][wid]) changed = 1;
                Kbuf[cur ^ 1][wid] = bb;
            }
            __syncthreads();
            int ch = changed;
            __syncthreads();
            if (tid == 0) changed = 0;
            cur ^= 1;
            if (!ch) break;
            __syncthreads();
        }
        __syncthreads();
        if (tid < 512 && tid < M) {
            if ((Kbuf[cur][tid >> 6] >> (tid & 63)) & 1ull) {
                int i = order_s[tid];
                atomicOr(&keep32[i >> 5], 1u << (i & 31));
            }
        }
    } else if (M > 0) {
        // --- generic sequential fallback (M > 512) ---
        if (tid < 64) {
            unsigned long long rem = 0ull;
            int lo = lane * 64;
            if (M > lo) rem = (M - lo >= 64) ? ~0ull : ((1ull << (M - lo)) - 1ull);
            for (int guard = 0; guard < N_DET; guard++) {
                unsigned long long vote = __ballot(rem != 0ull);
                if (!vote) break;
                int w = __builtin_ctzll(vote);
                unsigned long long wd = __shfl(rem, w, 64);
                int b = __builtin_ctzll(wd);
                int p = w * 64 + b;
                int i = order_s[p];
                if (lane == 0) atomicOr(&keep32[i >> 5], 1u << (i & 31));
                unsigned long long rowv = (lane < MW) ? S2[p * MW + lane] : 0ull;
                rem &= ~rowv;
                if (lane == w) rem &= ~(1ull << b);
            }
        }
    }
    __syncthreads();

    int c0 = 0, c1 = 0;
    for (int n = tid; n < N_DET; n += 1024) {
        bool kp = (keep32[n >> 5] >> (n & 31)) & 1u;
        float a = cls0[n], b = cls1[n];
        float mxc = fmaxf(a, b);
        bool m0 = kp && (a == mxc);
        bool m1 = kp && (b == mxc);
        float x = xx[n], y = yy[n];
        out[2 + 0 * N_DET * 2 + n * 2 + 0] = m0 ? x : 0.f;
        out[2 + 0 * N_DET * 2 + n * 2 + 1] = m0 ? y : 0.f;
        out[2 + 1 * N_DET * 2 + n * 2 + 0] = m1 ? x : 0.f;
        out[2 + 1 * N_DET * 2 + n * 2 + 1] = m1 ? y : 0.f;
        float kf = kp ? 1.f : 0.f;
#pragma unroll
        for (int k = 0; k < 8; k++)
            out[2 + 2 * N_DET * 2 + n * 8 + k] = rect[n * 8 + k] * kf;
        c0 += m0 ? 1 : 0;
        c1 += m1 ? 1 : 0;
    }
    if (c0) atomicAdd(&cnt_s[0], c0);
    if (c1) atomicAdd(&cnt_s[1], c1);
    __syncthreads();
    if (tid == 0) { out[0] = (float)cnt_s[0]; out[1] = (float)cnt_s[1]; }
}

// ---------------- launch ----------------
extern "C" void kernel_launch(void* const* d_in, const int* in_sizes, int n_in,
                              void* d_out, int out_size, void* d_ws, size_t ws_size,
                              hipStream_t stream) {
    const float* out3 = (const float*)d_in[0];
    const float* out4 = (const float*)d_in[1];
    const float* out5 = (const float*)d_in[2];
    const float* o1l3 = (const float*)d_in[3];
    const float* o1l4 = (const float*)d_in[4];
    const float* o1l5 = (const float*)d_in[5];
    const float* ofl3 = (const float*)d_in[6];
    const float* ofl4 = (const float*)d_in[7];
    const float* ofl5 = (const float*)d_in[8];
    float* out = (float*)d_out;

    const int N = N_DET;
    float* wsf  = (float*)d_ws;
    float* conf = wsf + 0 * N;
    float* cls0 = wsf + 1 * N;
    float* cls1 = wsf + 2 * N;
    float* xx   = wsf + 3 * N;
    float* yy   = wsf + 4 * N;
    float* a5   = wsf + 5 * N;
    float* ccx  = wsf + 6 * N;
    float* ccy  = wsf + 7 * N;
    float* rr   = wsf + 8 * N;
    float* rect = wsf + 9 * N;       // 8N
    float* cor  = wsf + 17 * N;      // 8N
    int* mask   = (int*)(wsf + 25 * N);  // N
    int* order  = mask + N;              // N
    int* Mcnt   = order + N;
    int* pairCnt = Mcnt + 1;
    // 8B-align for u64 (27N+2 words is odd in u64 units -> pad 2 words)
    unsigned long long* S2 = (unsigned long long*)(wsf + 27 * N + 4);   // N*NW u64 max
    // pair list overlaid past the fast-path S2 extent (M*MW*8 <= 32768 B when MW<=8)
    unsigned int* pairs = (unsigned int*)((char*)S2 + 32768);

    k_decode<<<(N + 255) / 256, 256, 0, stream>>>(out3, out4, out5, o1l3, o1l4, o1l5,
                                                  ofl3, ofl4, ofl5,
                                                  conf, cls0, cls1, xx, yy, a5,
                                                  ccx, ccy, rr, rect, cor, mask, Mcnt, pairCnt);
    k_order<<<N, 64, 0, stream>>>(conf, mask, order, Mcnt);
    k_pairs_a<<<(N * NW) / 4, 256, 0, stream>>>(rect, cor, a5, xx, yy, ccx, ccy, rr,
                                                order, Mcnt, S2, pairs, pairCnt);
    k_pairs_b<<<128, 256, 0, stream>>>(cor, a5, order, Mcnt, pairCnt, pairs, S2);
    k_scan_out<<<1, 1024, 0, stream>>>(cls0, cls1, xx, yy, rect, order, Mcnt, S2, out);
}